// Round 2
// baseline (119.102 us; speedup 1.0000x reference)
//
#include <hip/hip_runtime.h>

// 5-layer MLP: [B,64] -> 32 -> 12 -> 8 -> 6 -> 2, ReLU between, fp32 throughout.
// One thread per row; x staged through LDS so global loads are coalesced.
// LDS tile: row-major, stride 65 floats (65 mod 32 == 1 -> 2 lanes/bank on
// both the scatter-writes and the per-thread row reads == conflict-free).

#define BLOCK 256
#define RSTRIDE 65  // 64 + 1 pad

template <int IN, int OUT, bool RELU>
__device__ __forceinline__ void layer(const float* __restrict__ W,
                                      const float* __restrict__ b,
                                      const float* h_in, float* h_out) {
#pragma unroll
    for (int o = 0; o < OUT; ++o) h_out[o] = b[o];
#pragma unroll
    for (int i = 0; i < IN; ++i) {
        const float v = h_in[i];
#pragma unroll
        for (int o = 0; o < OUT; ++o) {
            h_out[o] = fmaf(v, W[i * OUT + o], h_out[o]);
        }
    }
    if (RELU) {
#pragma unroll
        for (int o = 0; o < OUT; ++o) h_out[o] = fmaxf(h_out[o], 0.0f);
    }
}

__global__ __launch_bounds__(BLOCK) void mlp_kernel(
        const float* __restrict__ x,
        const float* __restrict__ W0, const float* __restrict__ b0,
        const float* __restrict__ W1, const float* __restrict__ b1,
        const float* __restrict__ W2, const float* __restrict__ b2,
        const float* __restrict__ W3, const float* __restrict__ b3,
        const float* __restrict__ W4, const float* __restrict__ b4,
        float* __restrict__ out, int nrows) {
    extern __shared__ float tile[];  // BLOCK * RSTRIDE floats

    const int t = threadIdx.x;
    const long long base = (long long)blockIdx.x * BLOCK;  // first row of tile

    // Cooperative coalesced load: 256 rows * 16 float4 = 4096 float4 / block.
    // Wave reads 64 consecutive float4 (1 KB contiguous) per iteration.
    const float4* xv = reinterpret_cast<const float4*>(x) + base * 16;
#pragma unroll
    for (int k = 0; k < 16; ++k) {
        const int idx = k * BLOCK + t;          // 0..4095
        const float4 v = xv[idx];
        const int r = idx >> 4;                 // row within tile
        const int e = (idx & 15) << 2;          // element offset within row
        float* dst = &tile[r * RSTRIDE + e];
        dst[0] = v.x; dst[1] = v.y; dst[2] = v.z; dst[3] = v.w;
    }
    __syncthreads();

    const float* xr = &tile[t * RSTRIDE];       // this thread's 64-float row

    float h0[32];
    layer<64, 32, true>(W0, b0, xr, h0);
    float h1[12];
    layer<32, 12, true>(W1, b1, h0, h1);
    float h2[8];
    layer<12, 8, true>(W2, b2, h1, h2);
    float h3[6];
    layer<8, 6, true>(W3, b3, h2, h3);
    float h4[2];
    layer<6, 2, false>(W4, b4, h3, h4);

    const long long row = base + t;
    if (row < nrows) {
        float2* outv = reinterpret_cast<float2*>(out);
        outv[row] = make_float2(h4[0], h4[1]);
    }
}

extern "C" void kernel_launch(void* const* d_in, const int* in_sizes, int n_in,
                              void* d_out, int out_size, void* d_ws, size_t ws_size,
                              hipStream_t stream) {
    const float* x  = (const float*)d_in[0];
    const float* W0 = (const float*)d_in[1];
    const float* b0 = (const float*)d_in[2];
    const float* W1 = (const float*)d_in[3];
    const float* b1 = (const float*)d_in[4];
    const float* W2 = (const float*)d_in[5];
    const float* b2 = (const float*)d_in[6];
    const float* W3 = (const float*)d_in[7];
    const float* b3 = (const float*)d_in[8];
    const float* W4 = (const float*)d_in[9];
    const float* b4 = (const float*)d_in[10];
    float* out = (float*)d_out;

    const int nrows = in_sizes[0] / 64;         // 1048576
    const int grid = (nrows + BLOCK - 1) / BLOCK;
    const size_t shmem = (size_t)BLOCK * RSTRIDE * sizeof(float);  // 66,560 B

    mlp_kernel<<<grid, BLOCK, shmem, stream>>>(x, W0, b0, W1, b1, W2, b2,
                                               W3, b3, W4, b4, out, nrows);
}

// Round 3
// 95.345 us; speedup vs baseline: 1.2492x; 1.2492x over previous
//
#include <hip/hip_runtime.h>

// 5-layer MLP: [B,64] -> 32 -> 12 -> 8 -> 6 -> 2, ReLU between, fp32.
// One thread per row. All 16 float4 row-loads issued back-to-back (fenced
// with sched_barrier so the compiler can't re-serialize them), weights on
// the scalar pipe via uniform compile-time indexing. No LDS, no barriers.

#define BLOCK 256

template <int IN, int OUT, bool RELU>
__device__ __forceinline__ void layer(const float* __restrict__ W,
                                      const float* __restrict__ b,
                                      const float* h_in, float* h_out) {
#pragma unroll
    for (int o = 0; o < OUT; ++o) h_out[o] = b[o];
#pragma unroll
    for (int i = 0; i < IN; ++i) {
        const float v = h_in[i];
#pragma unroll
        for (int o = 0; o < OUT; ++o) {
            h_out[o] = fmaf(v, W[i * OUT + o], h_out[o]);
        }
    }
    if (RELU) {
#pragma unroll
        for (int o = 0; o < OUT; ++o) h_out[o] = fmaxf(h_out[o], 0.0f);
    }
}

__global__ __launch_bounds__(BLOCK, 4) void mlp_kernel(
        const float* __restrict__ x,
        const float* __restrict__ W0, const float* __restrict__ b0,
        const float* __restrict__ W1, const float* __restrict__ b1,
        const float* __restrict__ W2, const float* __restrict__ b2,
        const float* __restrict__ W3, const float* __restrict__ b3,
        const float* __restrict__ W4, const float* __restrict__ b4,
        float* __restrict__ out, int nrows) {
    const int row = blockIdx.x * BLOCK + threadIdx.x;
    if (row >= nrows) return;

    // Issue ALL 16 row loads before any compute. sched_barrier(0) keeps the
    // compiler from sinking loads into the FMA chain (which would serialize
    // them and leave only ~2 outstanding -> latency-bound, as in R1).
    float4 xv[16];
    const float4* xp = reinterpret_cast<const float4*>(x + (size_t)row * 64);
#pragma unroll
    for (int k = 0; k < 16; ++k) xv[k] = xp[k];
    __builtin_amdgcn_sched_barrier(0);

    float xr[64];
#pragma unroll
    for (int k = 0; k < 16; ++k) {
        xr[4 * k + 0] = xv[k].x;
        xr[4 * k + 1] = xv[k].y;
        xr[4 * k + 2] = xv[k].z;
        xr[4 * k + 3] = xv[k].w;
    }

    float h0[32];
    layer<64, 32, true>(W0, b0, xr, h0);
    float h1[12];
    layer<32, 12, true>(W1, b1, h0, h1);
    float h2[8];
    layer<12, 8, true>(W2, b2, h1, h2);
    float h3[6];
    layer<8, 6, true>(W3, b3, h2, h3);
    float h4[2];
    layer<6, 2, false>(W4, b4, h3, h4);

    float2* outv = reinterpret_cast<float2*>(out);
    outv[row] = make_float2(h4[0], h4[1]);
}

extern "C" void kernel_launch(void* const* d_in, const int* in_sizes, int n_in,
                              void* d_out, int out_size, void* d_ws, size_t ws_size,
                              hipStream_t stream) {
    const float* x  = (const float*)d_in[0];
    const float* W0 = (const float*)d_in[1];
    const float* b0 = (const float*)d_in[2];
    const float* W1 = (const float*)d_in[3];
    const float* b1 = (const float*)d_in[4];
    const float* W2 = (const float*)d_in[5];
    const float* b2 = (const float*)d_in[6];
    const float* W3 = (const float*)d_in[7];
    const float* b3 = (const float*)d_in[8];
    const float* W4 = (const float*)d_in[9];
    const float* b4 = (const float*)d_in[10];
    float* out = (float*)d_out;

    const int nrows = in_sizes[0] / 64;  // 1048576
    const int grid = (nrows + BLOCK - 1) / BLOCK;
    mlp_kernel<<<grid, BLOCK, 0, stream>>>(x, W0, b0, W1, b1, W2, b2,
                                           W3, b3, W4, b4, out, nrows);
}